// Round 2
// baseline (948.199 us; speedup 1.0000x reference)
//
#include <hip/hip_runtime.h>
#include <math.h>

#define NENT 128
#define BB 16

__device__ __forceinline__ float sigf(float x) { return 1.0f / (1.0f + __expf(-x)); }

// 4-entity register-blocked 64-dot against a register-resident weight column.
#define GEMV4_BODY(NB, A0, A1, A2, A3)                                        \
    _Pragma("unroll")                                                         \
    for (int i4 = 0; i4 < 16; ++i4) {                                         \
        const float4 e0 = *(const float4*)&s_ee[(NB) + 0][i4 * 4];            \
        const float4 e1 = *(const float4*)&s_ee[(NB) + 1][i4 * 4];            \
        const float4 e2 = *(const float4*)&s_ee[(NB) + 2][i4 * 4];            \
        const float4 e3 = *(const float4*)&s_ee[(NB) + 3][i4 * 4];            \
        A0 = fmaf(e0.x, wr[i4 * 4 + 0], A0); A0 = fmaf(e0.y, wr[i4 * 4 + 1], A0); \
        A0 = fmaf(e0.z, wr[i4 * 4 + 2], A0); A0 = fmaf(e0.w, wr[i4 * 4 + 3], A0); \
        A1 = fmaf(e1.x, wr[i4 * 4 + 0], A1); A1 = fmaf(e1.y, wr[i4 * 4 + 1], A1); \
        A1 = fmaf(e1.z, wr[i4 * 4 + 2], A1); A1 = fmaf(e1.w, wr[i4 * 4 + 3], A1); \
        A2 = fmaf(e2.x, wr[i4 * 4 + 0], A2); A2 = fmaf(e2.y, wr[i4 * 4 + 1], A2); \
        A2 = fmaf(e2.z, wr[i4 * 4 + 2], A2); A2 = fmaf(e2.w, wr[i4 * 4 + 3], A2); \
        A3 = fmaf(e3.x, wr[i4 * 4 + 0], A3); A3 = fmaf(e3.y, wr[i4 * 4 + 1], A3); \
        A3 = fmaf(e3.z, wr[i4 * 4 + 2], A3); A3 = fmaf(e3.w, wr[i4 * 4 + 3], A3); \
    }

// ---------------- Kernel A: encoders + masked MHA -> combined into out[:,12:140)
__global__ __launch_bounds__(256) void ka_attention(
    const float* __restrict__ self_feat,   // (B,24)
    const float* __restrict__ entities,    // (B,128,12)
    const void*  __restrict__ mask_raw,    // (B,128) int32 or uint8
    const float* __restrict__ W_se, const float* __restrict__ b_se,
    const float* __restrict__ W_ee, const float* __restrict__ b_ee,
    const float* __restrict__ W_q,  const float* __restrict__ b_q,
    const float* __restrict__ W_k,  const float* __restrict__ b_k,
    const float* __restrict__ W_v,  const float* __restrict__ b_v,
    float* out)                            // (B,268)
{
    const int b = blockIdx.x;
    const int t = threadIdx.x;
    const int o = t & 63;       // output dim within 64
    const int sub = t >> 6;     // wave id 0..3
    const int h = o >> 4;       // head of this output dim

    __shared__ float s_ee[NENT][64];    // ent_embed, 32 KB
    __shared__ float s_emb[64];
    __shared__ float s_q[64];
    __shared__ float s_attn[4][NENT];   // scores -> attn weights
    __shared__ float s_part[4][64];

    // ---- mask dtype probe (uniform; int32 storage => all first-64 words in {0,1})
    bool mask_is_int = true;
    {
        const unsigned int* mw = (const unsigned int*)mask_raw;
        #pragma unroll
        for (int w0 = 0; w0 < 64; ++w0) mask_is_int = mask_is_int && (mw[w0] <= 1u);
    }

    // ---- self_embed (wave 0)
    if (t < 64) {
        float acc = b_se[o];
        #pragma unroll
        for (int i = 0; i < 24; ++i) acc = fmaf(self_feat[b * 24 + i], W_se[i * 64 + o], acc);
        s_emb[o] = fmaxf(acc, 0.0f);
    }
    __syncthreads();

    // ---- q (wave 0) + entity encoder (all waves)
    if (t < 64) {
        float acc = b_q[o];
        #pragma unroll 8
        for (int i = 0; i < 64; ++i) acc = fmaf(s_emb[i], W_q[i * 64 + o], acc);
        s_q[o] = acc;
    }
    {
        float we[12];
        #pragma unroll
        for (int i = 0; i < 12; ++i) we[i] = W_ee[i * 64 + o];
        const float bee = b_ee[o];
        const float* erow = entities + (size_t)b * (NENT * 12);
        for (int rep = 0; rep < 32; ++rep) {
            const int n = rep * 4 + sub;
            float acc = bee;
            #pragma unroll
            for (int i = 0; i < 12; ++i) acc = fmaf(erow[n * 12 + i], we[i], acc);
            s_ee[n][o] = fmaxf(acc, 0.0f);
        }
    }
    __syncthreads();

    // ---- K pass: k = ee @ W_k + b_k ; scores[h][n] = q.k / 4
    {
        float wr[64];
        #pragma unroll
        for (int i = 0; i < 64; ++i) wr[i] = W_k[i * 64 + o];
        const float bk = b_k[o];
        const float qo = s_q[o];
        for (int ng = 0; ng < 8; ++ng) {
            const int nb = ng * 16 + sub * 4;
            float a0 = bk, a1 = bk, a2 = bk, a3 = bk;
            GEMV4_BODY(nb, a0, a1, a2, a3)
            a0 *= qo; a1 *= qo; a2 *= qo; a3 *= qo;
            #pragma unroll
            for (int d = 1; d < 16; d <<= 1) {
                a0 += __shfl_xor(a0, d); a1 += __shfl_xor(a1, d);
                a2 += __shfl_xor(a2, d); a3 += __shfl_xor(a3, d);
            }
            if ((o & 15) == 0) {
                s_attn[h][nb + 0] = a0 * 0.25f; s_attn[h][nb + 1] = a1 * 0.25f;
                s_attn[h][nb + 2] = a2 * 0.25f; s_attn[h][nb + 3] = a3 * 0.25f;
            }
        }
    }
    __syncthreads();

    // ---- masked softmax: wave `sub` handles head `sub` (128 scores, 2/lane)
    {
        const int lane = o;
        float sc0 = s_attn[sub][lane];
        float sc1 = s_attn[sub][lane + 64];
        bool m0, m1;
        if (mask_is_int) {
            const int* mi = (const int*)mask_raw;
            m0 = mi[(size_t)b * NENT + lane]      != 0;
            m1 = mi[(size_t)b * NENT + lane + 64] != 0;
        } else {
            const unsigned char* mb = (const unsigned char*)mask_raw;
            m0 = mb[(size_t)b * NENT + lane]      != 0;
            m1 = mb[(size_t)b * NENT + lane + 64] != 0;
        }
        sc0 = m0 ? sc0 : -1e30f;
        sc1 = m1 ? sc1 : -1e30f;
        float mx = fmaxf(sc0, sc1);
        #pragma unroll
        for (int d = 1; d < 64; d <<= 1) mx = fmaxf(mx, __shfl_xor(mx, d));
        const float e0 = __expf(sc0 - mx), e1 = __expf(sc1 - mx);
        float sm = e0 + e1;
        #pragma unroll
        for (int d = 1; d < 64; d <<= 1) sm += __shfl_xor(sm, d);
        const float inv = 1.0f / sm;
        s_attn[sub][lane]      = e0 * inv;
        s_attn[sub][lane + 64] = e1 * inv;
    }
    __syncthreads();

    // ---- V pass: v = ee @ W_v + b_v ; attn_out[o] = sum_n attn[h][n] * v[n][o]
    {
        float wr[64];
        #pragma unroll
        for (int i = 0; i < 64; ++i) wr[i] = W_v[i * 64 + o];
        const float bv = b_v[o];
        float acc_o = 0.0f;
        for (int ng = 0; ng < 8; ++ng) {
            const int nb = ng * 16 + sub * 4;
            float a0 = bv, a1 = bv, a2 = bv, a3 = bv;
            GEMV4_BODY(nb, a0, a1, a2, a3)
            acc_o = fmaf(s_attn[h][nb + 0], a0, acc_o);
            acc_o = fmaf(s_attn[h][nb + 1], a1, acc_o);
            acc_o = fmaf(s_attn[h][nb + 2], a2, acc_o);
            acc_o = fmaf(s_attn[h][nb + 3], a3, acc_o);
        }
        s_part[sub][o] = acc_o;
    }
    __syncthreads();

    if (t < 64) {
        const float ao = s_part[0][o] + s_part[1][o] + s_part[2][o] + s_part[3][o];
        out[(size_t)b * 268 + 12 + o] = s_emb[o];   // combined[0:64)  = self_embed
        out[(size_t)b * 268 + 76 + o] = ao;         // combined[64:128)= attn_out
    }
}

// 128x128 GEMV over BB rows staged in LDS; weights from global (L2-resident).
__device__ __forceinline__ void gemv128(const float (*s_in)[128], float (*s_out)[128],
                                        const float* __restrict__ W,
                                        const float* __restrict__ bvec,
                                        int t, bool relu_)
{
    const int oo = t & 127;
    const int rb = (t >> 7) * 8;
    const float bv = bvec[oo];
    float acc[8];
    #pragma unroll
    for (int r = 0; r < 8; ++r) acc[r] = bv;
    #pragma unroll 4
    for (int i = 0; i < 128; ++i) {
        const float w = W[i * 128 + oo];
        #pragma unroll
        for (int r = 0; r < 8; ++r) acc[r] = fmaf(s_in[rb + r][i], w, acc[r]);
    }
    #pragma unroll
    for (int r = 0; r < 8; ++r) s_out[rb + r][oo] = relu_ ? fmaxf(acc[r], 0.0f) : acc[r];
}

// ---------------- Kernel B: MLP + LSTM + actor heads (16 rows per block)
__global__ __launch_bounds__(256) void kb_lstm_heads(
    const float* __restrict__ hx, const float* __restrict__ cx,
    const float* __restrict__ W_p1, const float* __restrict__ b_p1,
    const float* __restrict__ W_p2, const float* __restrict__ b_p2,
    const float* __restrict__ W_ih, const float* __restrict__ b_ih,
    const float* __restrict__ W_hh, const float* __restrict__ b_hh,
    const float* __restrict__ W_a,  const float* __restrict__ b_a,
    const float* __restrict__ W_mx, const float* __restrict__ b_mx,
    const float* __restrict__ W_my, const float* __restrict__ b_my,
    const float* __restrict__ W_fi, const float* __restrict__ b_fi,
    const float* __restrict__ W_he, const float* __restrict__ b_he,
    const float* __restrict__ W_ra, const float* __restrict__ b_ra,
    const float* __restrict__ W_rb, const float* __restrict__ b_rb,
    float* out)   // aliases the combined staging area — no __restrict__
{
    const int t = threadIdx.x;
    const int r0 = blockIdx.x * BB;

    __shared__ float s_x[BB][128];   // combined -> reactive -> h
    __shared__ float s_y[BB][128];   // r1 -> features
    __shared__ float s_hx[BB][128];
    __shared__ float s_g[BB][512];   // gates

    // stage combined (written by kernel A into out[:,12:140)) and hx
    for (int idx = t; idx < BB * 128; idx += 256) {
        const int r = idx >> 7, j = idx & 127;
        s_x[r][j]  = out[(size_t)(r0 + r) * 268 + 12 + j];
        s_hx[r][j] = hx[(size_t)(r0 + r) * 128 + j];
    }
    __syncthreads();

    gemv128(s_x, s_y, W_p1, b_p1, t, true);    // r1
    __syncthreads();
    gemv128(s_y, s_x, W_p2, b_p2, t, true);    // reactive
    __syncthreads();

    // ---- LSTM gates: thread t owns output cols t and t+256 across all 16 rows
    {
        float acc1[16], acc2[16];
        const float bs1 = b_ih[t] + b_hh[t];
        const float bs2 = b_ih[t + 256] + b_hh[t + 256];
        #pragma unroll
        for (int r = 0; r < 16; ++r) { acc1[r] = bs1; acc2[r] = bs2; }
        #pragma unroll 4
        for (int i = 0; i < 128; ++i) {
            const float w1 = W_ih[i * 512 + t];
            const float w2 = W_ih[i * 512 + t + 256];
            #pragma unroll
            for (int r = 0; r < 16; ++r) {
                const float x = s_x[r][i];
                acc1[r] = fmaf(x, w1, acc1[r]);
                acc2[r] = fmaf(x, w2, acc2[r]);
            }
        }
        #pragma unroll 4
        for (int i = 0; i < 128; ++i) {
            const float w1 = W_hh[i * 512 + t];
            const float w2 = W_hh[i * 512 + t + 256];
            #pragma unroll
            for (int r = 0; r < 16; ++r) {
                const float x = s_hx[r][i];
                acc1[r] = fmaf(x, w1, acc1[r]);
                acc2[r] = fmaf(x, w2, acc2[r]);
            }
        }
        #pragma unroll
        for (int r = 0; r < 16; ++r) { s_g[r][t] = acc1[r]; s_g[r][t + 256] = acc2[r]; }
    }
    __syncthreads();

    // ---- LSTM elementwise (gate order i,f,g,o); write hx_new/cx_new; features in s_y
    for (int idx = t; idx < BB * 128; idx += 256) {
        const int r = idx >> 7, j = idx & 127;
        const float ig = s_g[r][j];
        const float fg = s_g[r][j + 128];
        const float gg = s_g[r][j + 256];
        const float og = s_g[r][j + 384];
        const float c_old = cx[(size_t)(r0 + r) * 128 + j];
        const float c_new = sigf(fg) * c_old + sigf(ig) * tanhf(gg);
        const float h_new = sigf(og) * tanhf(c_new);
        out[(size_t)(r0 + r) * 268 + 12 + j]  = h_new;
        out[(size_t)(r0 + r) * 268 + 140 + j] = c_new;
        s_y[r][j] = s_x[r][j] + h_new;   // features = reactive + hx_new
    }
    __syncthreads();

    gemv128(s_y, s_x, W_a, b_a, t, true);      // h
    __syncthreads();

    // ---- small heads: 12 scalar outputs per row
    if (t < BB * 12) {
        const int r = t / 12, w = t % 12;
        const float* Wm; const float* bm; int nc, c, off;
        if (w < 3)       { Wm = W_mx; bm = b_mx; nc = 3; c = w;     off = w;  }
        else if (w < 6)  { Wm = W_my; bm = b_my; nc = 3; c = w - 3; off = w;  }
        else if (w < 8)  { Wm = W_fi; bm = b_fi; nc = 2; c = w - 6; off = w;  }
        else if (w < 10) { Wm = W_he; bm = b_he; nc = 2; c = w - 8; off = w;  }
        else if (w == 10){ Wm = W_ra; bm = b_ra; nc = 1; c = 0;     off = 10; }
        else             { Wm = W_rb; bm = b_rb; nc = 1; c = 0;     off = 11; }
        float acc = bm[c];
        for (int i = 0; i < 128; ++i) acc = fmaf(s_x[r][i], Wm[i * nc + c], acc);
        if (w >= 10) acc = fmaxf(acc, 0.0f) + log1pf(__expf(-fabsf(acc))) + 1.0f;
        out[(size_t)(r0 + r) * 268 + off] = acc;
    }
}

extern "C" void kernel_launch(void* const* d_in, const int* in_sizes, int n_in,
                              void* d_out, int out_size, void* d_ws, size_t ws_size,
                              hipStream_t stream) {
    (void)n_in; (void)out_size; (void)d_ws; (void)ws_size;
    const float* self_feat = (const float*)d_in[0];
    const float* entities  = (const float*)d_in[1];
    const void*  mask      = d_in[2];
    const float* hx  = (const float*)d_in[3];
    const float* cx  = (const float*)d_in[4];
    const float* W_se = (const float*)d_in[5],  *b_se = (const float*)d_in[6];
    const float* W_ee = (const float*)d_in[7],  *b_ee = (const float*)d_in[8];
    const float* W_q  = (const float*)d_in[9],  *b_q  = (const float*)d_in[10];
    const float* W_k  = (const float*)d_in[11], *b_k  = (const float*)d_in[12];
    const float* W_v  = (const float*)d_in[13], *b_v  = (const float*)d_in[14];
    const float* W_p1 = (const float*)d_in[15], *b_p1 = (const float*)d_in[16];
    const float* W_p2 = (const float*)d_in[17], *b_p2 = (const float*)d_in[18];
    const float* W_ih = (const float*)d_in[19], *b_ih = (const float*)d_in[20];
    const float* W_hh = (const float*)d_in[21], *b_hh = (const float*)d_in[22];
    const float* W_a  = (const float*)d_in[23], *b_a  = (const float*)d_in[24];
    const float* W_mx = (const float*)d_in[25], *b_mx = (const float*)d_in[26];
    const float* W_my = (const float*)d_in[27], *b_my = (const float*)d_in[28];
    const float* W_fi = (const float*)d_in[29], *b_fi = (const float*)d_in[30];
    const float* W_he = (const float*)d_in[31], *b_he = (const float*)d_in[32];
    const float* W_ra = (const float*)d_in[33], *b_ra = (const float*)d_in[34];
    const float* W_rb = (const float*)d_in[35], *b_rb = (const float*)d_in[36];
    float* out = (float*)d_out;

    const int B = in_sizes[0] / 24;   // 8192

    ka_attention<<<B, 256, 0, stream>>>(self_feat, entities, mask,
        W_se, b_se, W_ee, b_ee, W_q, b_q, W_k, b_k, W_v, b_v, out);
    kb_lstm_heads<<<B / BB, 256, 0, stream>>>(hx, cx,
        W_p1, b_p1, W_p2, b_p2, W_ih, b_ih, W_hh, b_hh, W_a, b_a,
        W_mx, b_mx, W_my, b_my, W_fi, b_fi, W_he, b_he, W_ra, b_ra, W_rb, b_rb, out);
}

// Round 3
// 947.959 us; speedup vs baseline: 1.0003x; 1.0003x over previous
//
#include <hip/hip_runtime.h>
#include <math.h>

#define NENT 128
#define BB 16

__device__ __forceinline__ float sigf(float x) { return 1.0f / (1.0f + __expf(-x)); }

// 4-entity register-blocked 64-dot against a register-resident weight column.
#define GEMV4_BODY(NB, A0, A1, A2, A3)                                        \
    _Pragma("unroll")                                                         \
    for (int i4 = 0; i4 < 16; ++i4) {                                         \
        const float4 e0 = *(const float4*)&s_ee[(NB) + 0][i4 * 4];            \
        const float4 e1 = *(const float4*)&s_ee[(NB) + 1][i4 * 4];            \
        const float4 e2 = *(const float4*)&s_ee[(NB) + 2][i4 * 4];            \
        const float4 e3 = *(const float4*)&s_ee[(NB) + 3][i4 * 4];            \
        A0 = fmaf(e0.x, wr[i4 * 4 + 0], A0); A0 = fmaf(e0.y, wr[i4 * 4 + 1], A0); \
        A0 = fmaf(e0.z, wr[i4 * 4 + 2], A0); A0 = fmaf(e0.w, wr[i4 * 4 + 3], A0); \
        A1 = fmaf(e1.x, wr[i4 * 4 + 0], A1); A1 = fmaf(e1.y, wr[i4 * 4 + 1], A1); \
        A1 = fmaf(e1.z, wr[i4 * 4 + 2], A1); A1 = fmaf(e1.w, wr[i4 * 4 + 3], A1); \
        A2 = fmaf(e2.x, wr[i4 * 4 + 0], A2); A2 = fmaf(e2.y, wr[i4 * 4 + 1], A2); \
        A2 = fmaf(e2.z, wr[i4 * 4 + 2], A2); A2 = fmaf(e2.w, wr[i4 * 4 + 3], A2); \
        A3 = fmaf(e3.x, wr[i4 * 4 + 0], A3); A3 = fmaf(e3.y, wr[i4 * 4 + 1], A3); \
        A3 = fmaf(e3.z, wr[i4 * 4 + 2], A3); A3 = fmaf(e3.w, wr[i4 * 4 + 3], A3); \
    }

// ---------------- Kernel A: encoders + masked MHA -> combined into out[:,12:140)
__global__ __launch_bounds__(256) void ka_attention(
    const float* __restrict__ self_feat,   // (B,24)
    const float* __restrict__ entities,    // (B,128,12)
    const void*  __restrict__ mask_raw,    // (B,128) int32 or uint8
    const float* __restrict__ W_se, const float* __restrict__ b_se,
    const float* __restrict__ W_ee, const float* __restrict__ b_ee,
    const float* __restrict__ W_q,  const float* __restrict__ b_q,
    const float* __restrict__ W_k,  const float* __restrict__ b_k,
    const float* __restrict__ W_v,  const float* __restrict__ b_v,
    float* out)                            // (B,268)
{
    const int b = blockIdx.x;
    const int t = threadIdx.x;
    const int o = t & 63;       // output dim within 64
    const int sub = t >> 6;     // wave id 0..3
    const int h = o >> 4;       // head of this output dim

    __shared__ float s_ee[NENT][64];    // ent_embed, 32 KB
    __shared__ float s_emb[64];
    __shared__ float s_q[64];
    __shared__ float s_attn[4][NENT];   // scores -> attn weights
    __shared__ float s_part[4][64];

    // ---- mask dtype probe (uniform; int32 storage => all first-64 words in {0,1})
    bool mask_is_int = true;
    {
        const unsigned int* mw = (const unsigned int*)mask_raw;
        #pragma unroll
        for (int w0 = 0; w0 < 64; ++w0) mask_is_int = mask_is_int && (mw[w0] <= 1u);
    }

    // ---- self_embed (wave 0)
    if (t < 64) {
        float acc = b_se[o];
        #pragma unroll
        for (int i = 0; i < 24; ++i) acc = fmaf(self_feat[b * 24 + i], W_se[i * 64 + o], acc);
        s_emb[o] = fmaxf(acc, 0.0f);
    }
    __syncthreads();

    // ---- q (wave 0) + entity encoder (all waves)
    if (t < 64) {
        float acc = b_q[o];
        #pragma unroll 8
        for (int i = 0; i < 64; ++i) acc = fmaf(s_emb[i], W_q[i * 64 + o], acc);
        s_q[o] = acc;
    }
    {
        float we[12];
        #pragma unroll
        for (int i = 0; i < 12; ++i) we[i] = W_ee[i * 64 + o];
        const float bee = b_ee[o];
        const float* erow = entities + (size_t)b * (NENT * 12);
        for (int rep = 0; rep < 32; ++rep) {
            const int n = rep * 4 + sub;
            float acc = bee;
            #pragma unroll
            for (int i = 0; i < 12; ++i) acc = fmaf(erow[n * 12 + i], we[i], acc);
            s_ee[n][o] = fmaxf(acc, 0.0f);
        }
    }
    __syncthreads();

    // ---- K pass: k = ee @ W_k + b_k ; scores[h][n] = q.k / 4
    {
        float wr[64];
        #pragma unroll
        for (int i = 0; i < 64; ++i) wr[i] = W_k[i * 64 + o];
        const float bk = b_k[o];
        const float qo = s_q[o];
        for (int ng = 0; ng < 8; ++ng) {
            const int nb = ng * 16 + sub * 4;
            float a0 = bk, a1 = bk, a2 = bk, a3 = bk;
            GEMV4_BODY(nb, a0, a1, a2, a3)
            a0 *= qo; a1 *= qo; a2 *= qo; a3 *= qo;
            #pragma unroll
            for (int d = 1; d < 16; d <<= 1) {
                a0 += __shfl_xor(a0, d); a1 += __shfl_xor(a1, d);
                a2 += __shfl_xor(a2, d); a3 += __shfl_xor(a3, d);
            }
            if ((o & 15) == 0) {
                s_attn[h][nb + 0] = a0 * 0.25f; s_attn[h][nb + 1] = a1 * 0.25f;
                s_attn[h][nb + 2] = a2 * 0.25f; s_attn[h][nb + 3] = a3 * 0.25f;
            }
        }
    }
    __syncthreads();

    // ---- masked softmax: wave `sub` handles head `sub` (128 scores, 2/lane)
    {
        const int lane = o;
        float sc0 = s_attn[sub][lane];
        float sc1 = s_attn[sub][lane + 64];
        bool m0, m1;
        if (mask_is_int) {
            const int* mi = (const int*)mask_raw;
            m0 = mi[(size_t)b * NENT + lane]      != 0;
            m1 = mi[(size_t)b * NENT + lane + 64] != 0;
        } else {
            const unsigned char* mb = (const unsigned char*)mask_raw;
            m0 = mb[(size_t)b * NENT + lane]      != 0;
            m1 = mb[(size_t)b * NENT + lane + 64] != 0;
        }
        sc0 = m0 ? sc0 : -1e30f;
        sc1 = m1 ? sc1 : -1e30f;
        float mx = fmaxf(sc0, sc1);
        #pragma unroll
        for (int d = 1; d < 64; d <<= 1) mx = fmaxf(mx, __shfl_xor(mx, d));
        const float e0 = __expf(sc0 - mx), e1 = __expf(sc1 - mx);
        float sm = e0 + e1;
        #pragma unroll
        for (int d = 1; d < 64; d <<= 1) sm += __shfl_xor(sm, d);
        const float inv = 1.0f / sm;
        s_attn[sub][lane]      = e0 * inv;
        s_attn[sub][lane + 64] = e1 * inv;
    }
    __syncthreads();

    // ---- V pass: v = ee @ W_v + b_v ; attn_out[o] = sum_n attn[h][n] * v[n][o]
    {
        float wr[64];
        #pragma unroll
        for (int i = 0; i < 64; ++i) wr[i] = W_v[i * 64 + o];
        const float bv = b_v[o];
        float acc_o = 0.0f;
        for (int ng = 0; ng < 8; ++ng) {
            const int nb = ng * 16 + sub * 4;
            float a0 = bv, a1 = bv, a2 = bv, a3 = bv;
            GEMV4_BODY(nb, a0, a1, a2, a3)
            acc_o = fmaf(s_attn[h][nb + 0], a0, acc_o);
            acc_o = fmaf(s_attn[h][nb + 1], a1, acc_o);
            acc_o = fmaf(s_attn[h][nb + 2], a2, acc_o);
            acc_o = fmaf(s_attn[h][nb + 3], a3, acc_o);
        }
        s_part[sub][o] = acc_o;
    }
    __syncthreads();

    if (t < 64) {
        const float ao = s_part[0][o] + s_part[1][o] + s_part[2][o] + s_part[3][o];
        out[(size_t)b * 268 + 12 + o] = s_emb[o];   // combined[0:64)  = self_embed
        out[(size_t)b * 268 + 76 + o] = ao;         // combined[64:128)= attn_out
    }
}

// 128x128 GEMV over BB rows staged in LDS; weights from global (L2-resident).
__device__ __forceinline__ void gemv128(const float (*s_in)[128], float (*s_out)[128],
                                        const float* __restrict__ W,
                                        const float* __restrict__ bvec,
                                        int t, bool relu_)
{
    const int oo = t & 127;
    const int rb = (t >> 7) * 8;
    const float bv = bvec[oo];
    float acc[8];
    #pragma unroll
    for (int r = 0; r < 8; ++r) acc[r] = bv;
    #pragma unroll 4
    for (int i = 0; i < 128; ++i) {
        const float w = W[i * 128 + oo];
        #pragma unroll
        for (int r = 0; r < 8; ++r) acc[r] = fmaf(s_in[rb + r][i], w, acc[r]);
    }
    #pragma unroll
    for (int r = 0; r < 8; ++r) s_out[rb + r][oo] = relu_ ? fmaxf(acc[r], 0.0f) : acc[r];
}

// ---------------- Kernel B: MLP + LSTM + actor heads (16 rows per block)
__global__ __launch_bounds__(256) void kb_lstm_heads(
    const float* __restrict__ hx, const float* __restrict__ cx,
    const float* __restrict__ W_p1, const float* __restrict__ b_p1,
    const float* __restrict__ W_p2, const float* __restrict__ b_p2,
    const float* __restrict__ W_ih, const float* __restrict__ b_ih,
    const float* __restrict__ W_hh, const float* __restrict__ b_hh,
    const float* __restrict__ W_a,  const float* __restrict__ b_a,
    const float* __restrict__ W_mx, const float* __restrict__ b_mx,
    const float* __restrict__ W_my, const float* __restrict__ b_my,
    const float* __restrict__ W_fi, const float* __restrict__ b_fi,
    const float* __restrict__ W_he, const float* __restrict__ b_he,
    const float* __restrict__ W_ra, const float* __restrict__ b_ra,
    const float* __restrict__ W_rb, const float* __restrict__ b_rb,
    float* out)   // aliases the combined staging area — no __restrict__
{
    const int t = threadIdx.x;
    const int r0 = blockIdx.x * BB;

    __shared__ float s_x[BB][128];   // combined -> reactive -> h
    __shared__ float s_y[BB][128];   // r1 -> features
    __shared__ float s_hx[BB][128];
    __shared__ float s_g[BB][512];   // gates

    // stage combined (written by kernel A into out[:,12:140)) and hx
    for (int idx = t; idx < BB * 128; idx += 256) {
        const int r = idx >> 7, j = idx & 127;
        s_x[r][j]  = out[(size_t)(r0 + r) * 268 + 12 + j];
        s_hx[r][j] = hx[(size_t)(r0 + r) * 128 + j];
    }
    __syncthreads();

    gemv128(s_x, s_y, W_p1, b_p1, t, true);    // r1
    __syncthreads();
    gemv128(s_y, s_x, W_p2, b_p2, t, true);    // reactive
    __syncthreads();

    // ---- LSTM gates: thread t owns output cols t and t+256 across all 16 rows
    {
        float acc1[16], acc2[16];
        const float bs1 = b_ih[t] + b_hh[t];
        const float bs2 = b_ih[t + 256] + b_hh[t + 256];
        #pragma unroll
        for (int r = 0; r < 16; ++r) { acc1[r] = bs1; acc2[r] = bs2; }
        #pragma unroll 4
        for (int i = 0; i < 128; ++i) {
            const float w1 = W_ih[i * 512 + t];
            const float w2 = W_ih[i * 512 + t + 256];
            #pragma unroll
            for (int r = 0; r < 16; ++r) {
                const float x = s_x[r][i];
                acc1[r] = fmaf(x, w1, acc1[r]);
                acc2[r] = fmaf(x, w2, acc2[r]);
            }
        }
        #pragma unroll 4
        for (int i = 0; i < 128; ++i) {
            const float w1 = W_hh[i * 512 + t];
            const float w2 = W_hh[i * 512 + t + 256];
            #pragma unroll
            for (int r = 0; r < 16; ++r) {
                const float x = s_hx[r][i];
                acc1[r] = fmaf(x, w1, acc1[r]);
                acc2[r] = fmaf(x, w2, acc2[r]);
            }
        }
        #pragma unroll
        for (int r = 0; r < 16; ++r) { s_g[r][t] = acc1[r]; s_g[r][t + 256] = acc2[r]; }
    }
    __syncthreads();

    // ---- LSTM elementwise (gate order i,f,g,o); write hx_new/cx_new; features in s_y
    for (int idx = t; idx < BB * 128; idx += 256) {
        const int r = idx >> 7, j = idx & 127;
        const float ig = s_g[r][j];
        const float fg = s_g[r][j + 128];
        const float gg = s_g[r][j + 256];
        const float og = s_g[r][j + 384];
        const float c_old = cx[(size_t)(r0 + r) * 128 + j];
        const float c_new = sigf(fg) * c_old + sigf(ig) * tanhf(gg);
        const float h_new = sigf(og) * tanhf(c_new);
        out[(size_t)(r0 + r) * 268 + 12 + j]  = h_new;
        out[(size_t)(r0 + r) * 268 + 140 + j] = c_new;
        s_y[r][j] = s_x[r][j] + h_new;   // features = reactive + hx_new
    }
    __syncthreads();

    gemv128(s_y, s_x, W_a, b_a, t, true);      // h
    __syncthreads();

    // ---- small heads: 12 scalar outputs per row
    if (t < BB * 12) {
        const int r = t / 12, w = t % 12;
        const float* Wm; const float* bm; int nc, c, off;
        if (w < 3)       { Wm = W_mx; bm = b_mx; nc = 3; c = w;     off = w;  }
        else if (w < 6)  { Wm = W_my; bm = b_my; nc = 3; c = w - 3; off = w;  }
        else if (w < 8)  { Wm = W_fi; bm = b_fi; nc = 2; c = w - 6; off = w;  }
        else if (w < 10) { Wm = W_he; bm = b_he; nc = 2; c = w - 8; off = w;  }
        else if (w == 10){ Wm = W_ra; bm = b_ra; nc = 1; c = 0;     off = 10; }
        else             { Wm = W_rb; bm = b_rb; nc = 1; c = 0;     off = 11; }
        float acc = bm[c];
        for (int i = 0; i < 128; ++i) acc = fmaf(s_x[r][i], Wm[i * nc + c], acc);
        if (w >= 10) acc = fmaxf(acc, 0.0f) + log1pf(__expf(-fabsf(acc))) + 1.0f;
        out[(size_t)(r0 + r) * 268 + off] = acc;
    }
}

extern "C" void kernel_launch(void* const* d_in, const int* in_sizes, int n_in,
                              void* d_out, int out_size, void* d_ws, size_t ws_size,
                              hipStream_t stream) {
    (void)n_in; (void)out_size; (void)d_ws; (void)ws_size;
    const float* self_feat = (const float*)d_in[0];
    const float* entities  = (const float*)d_in[1];
    const void*  mask      = d_in[2];
    const float* hx  = (const float*)d_in[3];
    const float* cx  = (const float*)d_in[4];
    const float* W_se = (const float*)d_in[5],  *b_se = (const float*)d_in[6];
    const float* W_ee = (const float*)d_in[7],  *b_ee = (const float*)d_in[8];
    const float* W_q  = (const float*)d_in[9],  *b_q  = (const float*)d_in[10];
    const float* W_k  = (const float*)d_in[11], *b_k  = (const float*)d_in[12];
    const float* W_v  = (const float*)d_in[13], *b_v  = (const float*)d_in[14];
    const float* W_p1 = (const float*)d_in[15], *b_p1 = (const float*)d_in[16];
    const float* W_p2 = (const float*)d_in[17], *b_p2 = (const float*)d_in[18];
    const float* W_ih = (const float*)d_in[19], *b_ih = (const float*)d_in[20];
    const float* W_hh = (const float*)d_in[21], *b_hh = (const float*)d_in[22];
    const float* W_a  = (const float*)d_in[23], *b_a  = (const float*)d_in[24];
    const float* W_mx = (const float*)d_in[25], *b_mx = (const float*)d_in[26];
    const float* W_my = (const float*)d_in[27], *b_my = (const float*)d_in[28];
    const float* W_fi = (const float*)d_in[29], *b_fi = (const float*)d_in[30];
    const float* W_he = (const float*)d_in[31], *b_he = (const float*)d_in[32];
    const float* W_ra = (const float*)d_in[33], *b_ra = (const float*)d_in[34];
    const float* W_rb = (const float*)d_in[35], *b_rb = (const float*)d_in[36];
    float* out = (float*)d_out;

    const int B = in_sizes[0] / 24;   // 8192

    ka_attention<<<B, 256, 0, stream>>>(self_feat, entities, mask,
        W_se, b_se, W_ee, b_ee, W_q, b_q, W_k, b_k, W_v, b_v, out);
    kb_lstm_heads<<<B / BB, 256, 0, stream>>>(hx, cx,
        W_p1, b_p1, W_p2, b_p2, W_ih, b_ih, W_hh, b_hh, W_a, b_a,
        W_mx, b_mx, W_my, b_my, W_fi, b_fi, W_he, b_he, W_ra, b_ra, W_rb, b_rb, out);
}

// Round 4
// 947.215 us; speedup vs baseline: 1.0010x; 1.0008x over previous
//
#include <hip/hip_runtime.h>
#include <math.h>

#define NENT 128
#define BB 16

__device__ __forceinline__ float sigf(float x) { return 1.0f / (1.0f + __expf(-x)); }

// 4-entity register-blocked 64-dot against a register-resident weight column.
#define GEMV4_BODY(NB, A0, A1, A2, A3)                                        \
    _Pragma("unroll")                                                         \
    for (int i4 = 0; i4 < 16; ++i4) {                                         \
        const float4 e0 = *(const float4*)&s_ee[(NB) + 0][i4 * 4];            \
        const float4 e1 = *(const float4*)&s_ee[(NB) + 1][i4 * 4];            \
        const float4 e2 = *(const float4*)&s_ee[(NB) + 2][i4 * 4];            \
        const float4 e3 = *(const float4*)&s_ee[(NB) + 3][i4 * 4];            \
        A0 = fmaf(e0.x, wr[i4 * 4 + 0], A0); A0 = fmaf(e0.y, wr[i4 * 4 + 1], A0); \
        A0 = fmaf(e0.z, wr[i4 * 4 + 2], A0); A0 = fmaf(e0.w, wr[i4 * 4 + 3], A0); \
        A1 = fmaf(e1.x, wr[i4 * 4 + 0], A1); A1 = fmaf(e1.y, wr[i4 * 4 + 1], A1); \
        A1 = fmaf(e1.z, wr[i4 * 4 + 2], A1); A1 = fmaf(e1.w, wr[i4 * 4 + 3], A1); \
        A2 = fmaf(e2.x, wr[i4 * 4 + 0], A2); A2 = fmaf(e2.y, wr[i4 * 4 + 1], A2); \
        A2 = fmaf(e2.z, wr[i4 * 4 + 2], A2); A2 = fmaf(e2.w, wr[i4 * 4 + 3], A2); \
        A3 = fmaf(e3.x, wr[i4 * 4 + 0], A3); A3 = fmaf(e3.y, wr[i4 * 4 + 1], A3); \
        A3 = fmaf(e3.z, wr[i4 * 4 + 2], A3); A3 = fmaf(e3.w, wr[i4 * 4 + 3], A3); \
    }

// ---------------- Kernel A: encoders + masked MHA -> combined into out[:,12:140)
__global__ __launch_bounds__(256) void ka_attention(
    const float* __restrict__ self_feat,   // (B,24)
    const float* __restrict__ entities,    // (B,128,12)
    const void*  __restrict__ mask_raw,    // (B,128) int32 or uint8
    const float* __restrict__ W_se, const float* __restrict__ b_se,
    const float* __restrict__ W_ee, const float* __restrict__ b_ee,
    const float* __restrict__ W_q,  const float* __restrict__ b_q,
    const float* __restrict__ W_k,  const float* __restrict__ b_k,
    const float* __restrict__ W_v,  const float* __restrict__ b_v,
    float* out)                            // (B,268)
{
    const int b = blockIdx.x;
    const int t = threadIdx.x;
    const int o = t & 63;       // output dim within 64
    const int sub = t >> 6;     // wave id 0..3
    const int h = o >> 4;       // head of this output dim

    __shared__ float s_ee[NENT][64];    // ent_embed, 32 KB
    __shared__ float s_emb[64];
    __shared__ float s_q[64];
    __shared__ float s_attn[4][NENT];   // scores -> attn weights
    __shared__ float s_part[4][64];

    // ---- mask dtype probe (uniform; int32 storage => all first-64 words in {0,1})
    bool mask_is_int = true;
    {
        const unsigned int* mw = (const unsigned int*)mask_raw;
        #pragma unroll
        for (int w0 = 0; w0 < 64; ++w0) mask_is_int = mask_is_int && (mw[w0] <= 1u);
    }

    // ---- self_embed (wave 0)
    if (t < 64) {
        float acc = b_se[o];
        #pragma unroll
        for (int i = 0; i < 24; ++i) acc = fmaf(self_feat[b * 24 + i], W_se[i * 64 + o], acc);
        s_emb[o] = fmaxf(acc, 0.0f);
    }
    __syncthreads();

    // ---- q (wave 0) + entity encoder (all waves)
    if (t < 64) {
        float acc = b_q[o];
        #pragma unroll 8
        for (int i = 0; i < 64; ++i) acc = fmaf(s_emb[i], W_q[i * 64 + o], acc);
        s_q[o] = acc;
    }
    {
        float we[12];
        #pragma unroll
        for (int i = 0; i < 12; ++i) we[i] = W_ee[i * 64 + o];
        const float bee = b_ee[o];
        const float* erow = entities + (size_t)b * (NENT * 12);
        for (int rep = 0; rep < 32; ++rep) {
            const int n = rep * 4 + sub;
            float acc = bee;
            #pragma unroll
            for (int i = 0; i < 12; ++i) acc = fmaf(erow[n * 12 + i], we[i], acc);
            s_ee[n][o] = fmaxf(acc, 0.0f);
        }
    }
    __syncthreads();

    // ---- K pass: k = ee @ W_k + b_k ; scores[h][n] = q.k / 4
    {
        float wr[64];
        #pragma unroll
        for (int i = 0; i < 64; ++i) wr[i] = W_k[i * 64 + o];
        const float bk = b_k[o];
        const float qo = s_q[o];
        for (int ng = 0; ng < 8; ++ng) {
            const int nb = ng * 16 + sub * 4;
            float a0 = bk, a1 = bk, a2 = bk, a3 = bk;
            GEMV4_BODY(nb, a0, a1, a2, a3)
            a0 *= qo; a1 *= qo; a2 *= qo; a3 *= qo;
            #pragma unroll
            for (int d = 1; d < 16; d <<= 1) {
                a0 += __shfl_xor(a0, d); a1 += __shfl_xor(a1, d);
                a2 += __shfl_xor(a2, d); a3 += __shfl_xor(a3, d);
            }
            if ((o & 15) == 0) {
                s_attn[h][nb + 0] = a0 * 0.25f; s_attn[h][nb + 1] = a1 * 0.25f;
                s_attn[h][nb + 2] = a2 * 0.25f; s_attn[h][nb + 3] = a3 * 0.25f;
            }
        }
    }
    __syncthreads();

    // ---- masked softmax: wave `sub` handles head `sub` (128 scores, 2/lane)
    {
        const int lane = o;
        float sc0 = s_attn[sub][lane];
        float sc1 = s_attn[sub][lane + 64];
        bool m0, m1;
        if (mask_is_int) {
            const int* mi = (const int*)mask_raw;
            m0 = mi[(size_t)b * NENT + lane]      != 0;
            m1 = mi[(size_t)b * NENT + lane + 64] != 0;
        } else {
            const unsigned char* mb = (const unsigned char*)mask_raw;
            m0 = mb[(size_t)b * NENT + lane]      != 0;
            m1 = mb[(size_t)b * NENT + lane + 64] != 0;
        }
        sc0 = m0 ? sc0 : -1e30f;
        sc1 = m1 ? sc1 : -1e30f;
        float mx = fmaxf(sc0, sc1);
        #pragma unroll
        for (int d = 1; d < 64; d <<= 1) mx = fmaxf(mx, __shfl_xor(mx, d));
        const float e0 = __expf(sc0 - mx), e1 = __expf(sc1 - mx);
        float sm = e0 + e1;
        #pragma unroll
        for (int d = 1; d < 64; d <<= 1) sm += __shfl_xor(sm, d);
        const float inv = 1.0f / sm;
        s_attn[sub][lane]      = e0 * inv;
        s_attn[sub][lane + 64] = e1 * inv;
    }
    __syncthreads();

    // ---- V pass: v = ee @ W_v + b_v ; attn_out[o] = sum_n attn[h][n] * v[n][o]
    {
        float wr[64];
        #pragma unroll
        for (int i = 0; i < 64; ++i) wr[i] = W_v[i * 64 + o];
        const float bv = b_v[o];
        float acc_o = 0.0f;
        for (int ng = 0; ng < 8; ++ng) {
            const int nb = ng * 16 + sub * 4;
            float a0 = bv, a1 = bv, a2 = bv, a3 = bv;
            GEMV4_BODY(nb, a0, a1, a2, a3)
            acc_o = fmaf(s_attn[h][nb + 0], a0, acc_o);
            acc_o = fmaf(s_attn[h][nb + 1], a1, acc_o);
            acc_o = fmaf(s_attn[h][nb + 2], a2, acc_o);
            acc_o = fmaf(s_attn[h][nb + 3], a3, acc_o);
        }
        s_part[sub][o] = acc_o;
    }
    __syncthreads();

    if (t < 64) {
        const float ao = s_part[0][o] + s_part[1][o] + s_part[2][o] + s_part[3][o];
        out[(size_t)b * 268 + 12 + o] = s_emb[o];   // combined[0:64)  = self_embed
        out[(size_t)b * 268 + 76 + o] = ao;         // combined[64:128)= attn_out
    }
}

// 128x128 GEMV over BB rows staged in LDS; weights from global (L2-resident).
__device__ __forceinline__ void gemv128(const float (*s_in)[128], float (*s_out)[128],
                                        const float* __restrict__ W,
                                        const float* __restrict__ bvec,
                                        int t, bool relu_)
{
    const int oo = t & 127;
    const int rb = (t >> 7) * 8;
    const float bv = bvec[oo];
    float acc[8];
    #pragma unroll
    for (int r = 0; r < 8; ++r) acc[r] = bv;
    #pragma unroll 4
    for (int i = 0; i < 128; ++i) {
        const float w = W[i * 128 + oo];
        #pragma unroll
        for (int r = 0; r < 8; ++r) acc[r] = fmaf(s_in[rb + r][i], w, acc[r]);
    }
    #pragma unroll
    for (int r = 0; r < 8; ++r) s_out[rb + r][oo] = relu_ ? fmaxf(acc[r], 0.0f) : acc[r];
}

// ---------------- Kernel B: MLP + LSTM + actor heads (16 rows per block)
__global__ __launch_bounds__(256) void kb_lstm_heads(
    const float* __restrict__ hx, const float* __restrict__ cx,
    const float* __restrict__ W_p1, const float* __restrict__ b_p1,
    const float* __restrict__ W_p2, const float* __restrict__ b_p2,
    const float* __restrict__ W_ih, const float* __restrict__ b_ih,
    const float* __restrict__ W_hh, const float* __restrict__ b_hh,
    const float* __restrict__ W_a,  const float* __restrict__ b_a,
    const float* __restrict__ W_mx, const float* __restrict__ b_mx,
    const float* __restrict__ W_my, const float* __restrict__ b_my,
    const float* __restrict__ W_fi, const float* __restrict__ b_fi,
    const float* __restrict__ W_he, const float* __restrict__ b_he,
    const float* __restrict__ W_ra, const float* __restrict__ b_ra,
    const float* __restrict__ W_rb, const float* __restrict__ b_rb,
    float* out)   // aliases the combined staging area — no __restrict__
{
    const int t = threadIdx.x;
    const int r0 = blockIdx.x * BB;

    __shared__ float s_x[BB][128];   // combined -> reactive -> h
    __shared__ float s_y[BB][128];   // r1 -> features
    __shared__ float s_hx[BB][128];
    __shared__ float s_g[BB][512];   // gates

    // stage combined (written by kernel A into out[:,12:140)) and hx
    for (int idx = t; idx < BB * 128; idx += 256) {
        const int r = idx >> 7, j = idx & 127;
        s_x[r][j]  = out[(size_t)(r0 + r) * 268 + 12 + j];
        s_hx[r][j] = hx[(size_t)(r0 + r) * 128 + j];
    }
    __syncthreads();

    gemv128(s_x, s_y, W_p1, b_p1, t, true);    // r1
    __syncthreads();
    gemv128(s_y, s_x, W_p2, b_p2, t, true);    // reactive
    __syncthreads();

    // ---- LSTM gates: thread t owns output cols t and t+256 across all 16 rows
    {
        float acc1[16], acc2[16];
        const float bs1 = b_ih[t] + b_hh[t];
        const float bs2 = b_ih[t + 256] + b_hh[t + 256];
        #pragma unroll
        for (int r = 0; r < 16; ++r) { acc1[r] = bs1; acc2[r] = bs2; }
        #pragma unroll 4
        for (int i = 0; i < 128; ++i) {
            const float w1 = W_ih[i * 512 + t];
            const float w2 = W_ih[i * 512 + t + 256];
            #pragma unroll
            for (int r = 0; r < 16; ++r) {
                const float x = s_x[r][i];
                acc1[r] = fmaf(x, w1, acc1[r]);
                acc2[r] = fmaf(x, w2, acc2[r]);
            }
        }
        #pragma unroll 4
        for (int i = 0; i < 128; ++i) {
            const float w1 = W_hh[i * 512 + t];
            const float w2 = W_hh[i * 512 + t + 256];
            #pragma unroll
            for (int r = 0; r < 16; ++r) {
                const float x = s_hx[r][i];
                acc1[r] = fmaf(x, w1, acc1[r]);
                acc2[r] = fmaf(x, w2, acc2[r]);
            }
        }
        #pragma unroll
        for (int r = 0; r < 16; ++r) { s_g[r][t] = acc1[r]; s_g[r][t + 256] = acc2[r]; }
    }
    __syncthreads();

    // ---- LSTM elementwise (gate order i,f,g,o); write hx_new/cx_new; features in s_y
    for (int idx = t; idx < BB * 128; idx += 256) {
        const int r = idx >> 7, j = idx & 127;
        const float ig = s_g[r][j];
        const float fg = s_g[r][j + 128];
        const float gg = s_g[r][j + 256];
        const float og = s_g[r][j + 384];
        const float c_old = cx[(size_t)(r0 + r) * 128 + j];
        const float c_new = sigf(fg) * c_old + sigf(ig) * tanhf(gg);
        const float h_new = sigf(og) * tanhf(c_new);
        out[(size_t)(r0 + r) * 268 + 12 + j]  = h_new;
        out[(size_t)(r0 + r) * 268 + 140 + j] = c_new;
        s_y[r][j] = s_x[r][j] + h_new;   // features = reactive + hx_new
    }
    __syncthreads();

    gemv128(s_y, s_x, W_a, b_a, t, true);      // h
    __syncthreads();

    // ---- small heads: 12 scalar outputs per row
    if (t < BB * 12) {
        const int r = t / 12, w = t % 12;
        const float* Wm; const float* bm; int nc, c, off;
        if (w < 3)       { Wm = W_mx; bm = b_mx; nc = 3; c = w;     off = w;  }
        else if (w < 6)  { Wm = W_my; bm = b_my; nc = 3; c = w - 3; off = w;  }
        else if (w < 8)  { Wm = W_fi; bm = b_fi; nc = 2; c = w - 6; off = w;  }
        else if (w < 10) { Wm = W_he; bm = b_he; nc = 2; c = w - 8; off = w;  }
        else if (w == 10){ Wm = W_ra; bm = b_ra; nc = 1; c = 0;     off = 10; }
        else             { Wm = W_rb; bm = b_rb; nc = 1; c = 0;     off = 11; }
        float acc = bm[c];
        for (int i = 0; i < 128; ++i) acc = fmaf(s_x[r][i], Wm[i * nc + c], acc);
        if (w >= 10) acc = fmaxf(acc, 0.0f) + log1pf(__expf(-fabsf(acc))) + 1.0f;
        out[(size_t)(r0 + r) * 268 + off] = acc;
    }
}

extern "C" void kernel_launch(void* const* d_in, const int* in_sizes, int n_in,
                              void* d_out, int out_size, void* d_ws, size_t ws_size,
                              hipStream_t stream) {
    (void)n_in; (void)out_size; (void)d_ws; (void)ws_size;
    const float* self_feat = (const float*)d_in[0];
    const float* entities  = (const float*)d_in[1];
    const void*  mask      = d_in[2];
    const float* hx  = (const float*)d_in[3];
    const float* cx  = (const float*)d_in[4];
    const float* W_se = (const float*)d_in[5],  *b_se = (const float*)d_in[6];
    const float* W_ee = (const float*)d_in[7],  *b_ee = (const float*)d_in[8];
    const float* W_q  = (const float*)d_in[9],  *b_q  = (const float*)d_in[10];
    const float* W_k  = (const float*)d_in[11], *b_k  = (const float*)d_in[12];
    const float* W_v  = (const float*)d_in[13], *b_v  = (const float*)d_in[14];
    const float* W_p1 = (const float*)d_in[15], *b_p1 = (const float*)d_in[16];
    const float* W_p2 = (const float*)d_in[17], *b_p2 = (const float*)d_in[18];
    const float* W_ih = (const float*)d_in[19], *b_ih = (const float*)d_in[20];
    const float* W_hh = (const float*)d_in[21], *b_hh = (const float*)d_in[22];
    const float* W_a  = (const float*)d_in[23], *b_a  = (const float*)d_in[24];
    const float* W_mx = (const float*)d_in[25], *b_mx = (const float*)d_in[26];
    const float* W_my = (const float*)d_in[27], *b_my = (const float*)d_in[28];
    const float* W_fi = (const float*)d_in[29], *b_fi = (const float*)d_in[30];
    const float* W_he = (const float*)d_in[31], *b_he = (const float*)d_in[32];
    const float* W_ra = (const float*)d_in[33], *b_ra = (const float*)d_in[34];
    const float* W_rb = (const float*)d_in[35], *b_rb = (const float*)d_in[36];
    float* out = (float*)d_out;

    const int B = in_sizes[0] / 24;   // 8192

    ka_attention<<<B, 256, 0, stream>>>(self_feat, entities, mask,
        W_se, b_se, W_ee, b_ee, W_q, b_q, W_k, b_k, W_v, b_v, out);
    kb_lstm_heads<<<B / BB, 256, 0, stream>>>(hx, cx,
        W_p1, b_p1, W_p2, b_p2, W_ih, b_ih, W_hh, b_hh, W_a, b_a,
        W_mx, b_mx, W_my, b_my, W_fi, b_fi, W_he, b_he, W_ra, b_ra, W_rb, b_rb, out);
}